// Round 1
// baseline (433.373 us; speedup 1.0000x reference)
//
#include <hip/hip_runtime.h>
#include <stdint.h>

typedef __bf16 bf16;
typedef __bf16 bf16x4 __attribute__((ext_vector_type(4)));
typedef __bf16 bf16x8 __attribute__((ext_vector_type(8)));
typedef float  f32x4  __attribute__((ext_vector_type(4)));

#define MFMA16(a,b,c) __builtin_amdgcn_mfma_f32_16x16x32_bf16((a),(b),(c),0,0,0)

// LDS strides in elements (all rows 16B-aligned, ~2-way max bank aliasing)
#define XS_STR 104   // x window / o buffer [64][104] bf16
#define QK_STR 200   // q|k buffer [64][200] (cols 0..95 q, 96..191 k)
#define VT_STR 72    // v transposed [96][72]  (vT[d][m'])
#define SB_STR 72    // P buffer per head [64][72]

// weight prep: fp32 [K][N] -> bf16 [N][K] (transposed) in workspace
__global__ void prep_weights(const float* __restrict__ qkv_w,
                             const float* __restrict__ proj_w,
                             bf16* __restrict__ wT) {
    int i = blockIdx.x * 256 + threadIdx.x;
    if (i < 288 * 96) {
        int j = i / 96, c = i - j * 96;
        wT[i] = (bf16)qkv_w[c * 288 + j];
    } else if (i < 288 * 96 + 96 * 96) {
        int t = i - 288 * 96;
        int j = t / 96, c = t - j * 96;
        wT[i] = (bf16)proj_w[c * 96 + j];
    }
}

__global__ __launch_bounds__(256, 2)
void win_attn_kernel(const float* __restrict__ x,
                     const float* __restrict__ qkv_b,
                     const float* __restrict__ proj_b,
                     const bf16* __restrict__ qkvwT,   // [288][96] bf16
                     const bf16* __restrict__ projwT,  // [96][96] bf16
                     float* __restrict__ out)
{
    __shared__ bf16 lds_xo[64 * XS_STR];     // 13312 B : x window, then o
    __shared__ bf16 lds_qk[64 * QK_STR];     // 25600 B : q | k
    __shared__ bf16 lds_vT[96 * VT_STR];     // 13824 B : v^T
    __shared__ bf16 lds_S [3 * 64 * SB_STR]; // 27648 B : P per head

    const int tid  = threadIdx.x;
    const int wid  = tid >> 6;
    const int lane = tid & 63;
    const int lm   = lane & 15;   // m / n / col within 16-tile
    const int lq   = lane >> 4;   // quad 0..3

    const int wi = blockIdx.x;
    const int b  = wi >> 10;          // 1024 windows per batch image
    const int wr = wi & 1023;
    const int h0 = (wr >> 5) * 7;
    const int w0 = (wr & 31) * 7;

    // ---------------- Phase 0: stage x window -> bf16 LDS ----------------
    {
        const float* xbase = x + ((size_t)(b * 224 + h0) * 224 + w0) * 96;
        for (int t = tid; t < 49 * 24; t += 256) {
            int pix = t / 24, f = t - pix * 24;
            int pr = pix / 7, pc = pix - pr * 7;
            const float4 v = *(const float4*)(xbase + ((size_t)pr * 224 + pc) * 96 + f * 4);
            bf16x4 bv = { (bf16)v.x, (bf16)v.y, (bf16)v.z, (bf16)v.w };
            *(bf16x4*)&lds_xo[pix * XS_STR + f * 4] = bv;
        }
        bf16x4 z = { (bf16)0.f, (bf16)0.f, (bf16)0.f, (bf16)0.f };
        for (int t = tid; t < 15 * 24; t += 256) {   // zero M-pad rows 49..63
            int row = 49 + t / 24, f = t - (t / 24) * 24;
            *(bf16x4*)&lds_xo[row * XS_STR + f * 4] = z;
        }
    }
    __syncthreads();

    // ---------------- Phase 1: QKV = xs @ qkv_w + b  (M=64,N=288,K=96) ----------------
    {
        bf16x8 afr[4][3];
        #pragma unroll
        for (int mt = 0; mt < 4; ++mt)
            #pragma unroll
            for (int ks = 0; ks < 3; ++ks)
                afr[mt][ks] = *(const bf16x8*)&lds_xo[(mt * 16 + lm) * XS_STR + ks * 32 + lq * 8];

        for (int nt = wid; nt < 18; nt += 4) {
            const int j = nt * 16 + lm;
            bf16x8 bfr[3];
            #pragma unroll
            for (int ks = 0; ks < 3; ++ks)
                bfr[ks] = *(const bf16x8*)&qkvwT[(size_t)j * 96 + ks * 32 + lq * 8];
            const float bias = qkv_b[j];
            f32x4 acc[4];
            #pragma unroll
            for (int mt = 0; mt < 4; ++mt) acc[mt] = (f32x4){bias, bias, bias, bias};
            #pragma unroll
            for (int ks = 0; ks < 3; ++ks)
                #pragma unroll
                for (int mt = 0; mt < 4; ++mt)
                    acc[mt] = MFMA16(afr[mt][ks], bfr[ks], acc[mt]);
            if (j < 192) {      // q or k -> row-major q|k buffer (wave-uniform branch)
                #pragma unroll
                for (int mt = 0; mt < 4; ++mt)
                    #pragma unroll
                    for (int i = 0; i < 4; ++i)
                        lds_qk[(mt * 16 + lq * 4 + i) * QK_STR + j] = (bf16)acc[mt][i];
            } else {            // v -> transposed vT[d][m'], 4 rows pack to 8B write
                const int d = j - 192;
                #pragma unroll
                for (int mt = 0; mt < 4; ++mt) {
                    bf16x4 pv = { (bf16)acc[mt][0], (bf16)acc[mt][1],
                                  (bf16)acc[mt][2], (bf16)acc[mt][3] };
                    *(bf16x4*)&lds_vT[d * VT_STR + mt * 16 + lq * 4] = pv;
                }
            }
        }
    }
    __syncthreads();

    // ---------------- Phase 2: attention, wave h handles head h ----------------
    if (wid < 3) {
        const int h = wid;
        const f32x4 zf = {0.f, 0.f, 0.f, 0.f};
        bf16x8 aq[4], bk[4];
        #pragma unroll
        for (int mt = 0; mt < 4; ++mt)
            aq[mt] = *(const bf16x8*)&lds_qk[(mt * 16 + lm) * QK_STR + h * 32 + lq * 8];
        #pragma unroll
        for (int nt = 0; nt < 4; ++nt)
            bk[nt] = *(const bf16x8*)&lds_qk[(nt * 16 + lm) * QK_STR + 96 + h * 32 + lq * 8];
        f32x4 s[4][4];
        #pragma unroll
        for (int mt = 0; mt < 4; ++mt)
            #pragma unroll
            for (int nt = 0; nt < 4; ++nt)
                s[mt][nt] = MFMA16(aq[mt], bk[nt], zf);

        // masked online softmax per row (rows spread over quad*4+reg; cols over 16 lanes x 4 nt)
        const float scale = 0.17677669529663687f;  // 1/sqrt(32)
        const float log2e = 1.4426950408889634f;
        bf16* Sb = &lds_S[h * 64 * SB_STR];
        #pragma unroll
        for (int mt = 0; mt < 4; ++mt) {
            #pragma unroll
            for (int i = 0; i < 4; ++i) {
                float v[4];
                float mx = -3.0e38f;
                #pragma unroll
                for (int nt = 0; nt < 4; ++nt) {
                    const bool valid = (nt * 16 + lm) < 49;
                    v[nt] = valid ? s[mt][nt][i] * scale : -3.0e38f;
                    mx = fmaxf(mx, v[nt]);
                }
                mx = fmaxf(mx, __shfl_xor(mx, 1));
                mx = fmaxf(mx, __shfl_xor(mx, 2));
                mx = fmaxf(mx, __shfl_xor(mx, 4));
                mx = fmaxf(mx, __shfl_xor(mx, 8));
                float p[4], sum = 0.f;
                #pragma unroll
                for (int nt = 0; nt < 4; ++nt) {
                    const bool valid = (nt * 16 + lm) < 49;
                    p[nt] = valid ? exp2f((v[nt] - mx) * log2e) : 0.f;
                    sum += p[nt];
                }
                sum += __shfl_xor(sum, 1);
                sum += __shfl_xor(sum, 2);
                sum += __shfl_xor(sum, 4);
                sum += __shfl_xor(sum, 8);
                const float rinv = __builtin_amdgcn_rcpf(sum);
                const int row = mt * 16 + lq * 4 + i;
                #pragma unroll
                for (int nt = 0; nt < 4; ++nt)
                    Sb[row * SB_STR + nt * 16 + lm] = (bf16)(p[nt] * rinv);
            }
        }

        // PV: O_h = P @ V  (M=64, N=32, K=64)
        f32x4 oacc[4][2];
        #pragma unroll
        for (int mt = 0; mt < 4; ++mt)
            #pragma unroll
            for (int nt = 0; nt < 2; ++nt) oacc[mt][nt] = zf;
        #pragma unroll
        for (int ks = 0; ks < 2; ++ks) {
            bf16x8 ap[4], bv[2];
            #pragma unroll
            for (int mt = 0; mt < 4; ++mt)
                ap[mt] = *(const bf16x8*)&Sb[(mt * 16 + lm) * SB_STR + ks * 32 + lq * 8];
            #pragma unroll
            for (int nt = 0; nt < 2; ++nt)
                bv[nt] = *(const bf16x8*)&lds_vT[(h * 32 + nt * 16 + lm) * VT_STR + ks * 32 + lq * 8];
            #pragma unroll
            for (int mt = 0; mt < 4; ++mt)
                #pragma unroll
                for (int nt = 0; nt < 2; ++nt)
                    oacc[mt][nt] = MFMA16(ap[mt], bv[nt], oacc[mt][nt]);
        }
        #pragma unroll
        for (int mt = 0; mt < 4; ++mt)
            #pragma unroll
            for (int nt = 0; nt < 2; ++nt)
                #pragma unroll
                for (int i = 0; i < 4; ++i)
                    lds_xo[(mt * 16 + lq * 4 + i) * XS_STR + h * 32 + nt * 16 + lm] =
                        (bf16)oacc[mt][nt][i];
    }
    __syncthreads();

    // ---------------- Phase 3: proj (M=64,N=96,K=96), wave w owns m-tile w ----------------
    {
        const int mt = wid;
        bf16x8 ao[3];
        #pragma unroll
        for (int ks = 0; ks < 3; ++ks)
            ao[ks] = *(const bf16x8*)&lds_xo[(mt * 16 + lm) * XS_STR + ks * 32 + lq * 8];
        #pragma unroll
        for (int nt = 0; nt < 6; ++nt) {
            const int j = nt * 16 + lm;
            bf16x8 bp[3];
            #pragma unroll
            for (int ks = 0; ks < 3; ++ks)
                bp[ks] = *(const bf16x8*)&projwT[(size_t)j * 96 + ks * 32 + lq * 8];
            const float bias = proj_b[j];
            f32x4 acc = {bias, bias, bias, bias};
            #pragma unroll
            for (int ks = 0; ks < 3; ++ks)
                acc = MFMA16(ao[ks], bp[ks], acc);
            #pragma unroll
            for (int i = 0; i < 4; ++i) {
                const int l = mt * 16 + lq * 4 + i;
                if (l < 49) {
                    const int pr = l / 7, pc = l - pr * 7;
                    out[((size_t)(b * 224 + h0 + pr) * 224 + (w0 + pc)) * 96 + j] = acc[i];
                }
            }
        }
    }
}

extern "C" void kernel_launch(void* const* d_in, const int* in_sizes, int n_in,
                              void* d_out, int out_size, void* d_ws, size_t ws_size,
                              hipStream_t stream) {
    const float* x      = (const float*)d_in[0];
    const float* qkv_w  = (const float*)d_in[1];
    const float* qkv_b  = (const float*)d_in[2];
    const float* proj_w = (const float*)d_in[3];
    const float* proj_b = (const float*)d_in[4];
    float* out = (float*)d_out;

    bf16* wT = (bf16*)d_ws;                 // 288*96 + 96*96 bf16 = 73728 B
    const int n_w = 288 * 96 + 96 * 96;
    prep_weights<<<(n_w + 255) / 256, 256, 0, stream>>>(qkv_w, proj_w, wT);
    win_attn_kernel<<<8192, 256, 0, stream>>>(x, qkv_b, proj_b,
                                              wT, wT + 288 * 96, out);
}

// Round 2
// 367.103 us; speedup vs baseline: 1.1805x; 1.1805x over previous
//
#include <hip/hip_runtime.h>
#include <stdint.h>

typedef __bf16 bf16;
typedef __bf16 bf16x4 __attribute__((ext_vector_type(4)));
typedef __bf16 bf16x8 __attribute__((ext_vector_type(8)));
typedef float  f32x4  __attribute__((ext_vector_type(4)));

#define MFMA16(a,b,c) __builtin_amdgcn_mfma_f32_16x16x32_bf16((a),(b),(c),0,0,0)

// Region A: x window [64][104] bf16 (13312 B), later v^T [96][64] swizzled (12288 B)
// Region B: q|k [64][200] (25600 B), later S [3][64][72] (27648 B), later O [64][104]
#define XS_STR 104
#define QK_STR 200
#define SB_STR 72
#define S_HEAD 4608   // 64*72 elements per head

// weight prep: fp32 [K][N] -> bf16 [N][K] (transposed) in workspace
__global__ void prep_weights(const float* __restrict__ qkv_w,
                             const float* __restrict__ proj_w,
                             bf16* __restrict__ wT) {
    int i = blockIdx.x * 256 + threadIdx.x;
    if (i < 288 * 96) {
        int j = i / 96, c = i - j * 96;
        wT[i] = (bf16)qkv_w[c * 288 + j];
    } else if (i < 288 * 96 + 96 * 96) {
        int t = i - 288 * 96;
        int j = t / 96, c = t - j * 96;
        wT[i] = (bf16)proj_w[c * 96 + j];
    }
}

__global__ __launch_bounds__(256, 4)
void win_attn_kernel(const float* __restrict__ x,
                     const float* __restrict__ qkv_b,
                     const float* __restrict__ proj_b,
                     const bf16* __restrict__ qkvwT,   // [288][96] bf16
                     const bf16* __restrict__ projwT,  // [96][96] bf16
                     float* __restrict__ out)
{
    __shared__ bf16 ldsA[64 * XS_STR];   // 13312 B
    __shared__ bf16 ldsB[3 * 64 * SB_STR]; // 27648 B  (>= 64*QK_STR = 12800 elems)

    const int tid  = threadIdx.x;
    const int wid  = tid >> 6;
    const int lane = tid & 63;
    const int lm   = lane & 15;   // m / n / col within 16-tile
    const int lq   = lane >> 4;   // quad 0..3

    const int wi = blockIdx.x;
    const int b  = wi >> 10;          // 1024 windows per batch image
    const int wr = wi & 1023;
    const int h0 = (wr >> 5) * 7;
    const int w0 = (wr & 31) * 7;

    // ---------------- Phase 0: stage x window -> bf16 LDS (region A) ----------------
    {
        const float* xbase = x + ((size_t)(b * 224 + h0) * 224 + w0) * 96;
        for (int t = tid; t < 49 * 24; t += 256) {
            int pix = t / 24, f = t - pix * 24;
            int pr = pix / 7, pc = pix - pr * 7;
            const float4 v = *(const float4*)(xbase + ((size_t)pr * 224 + pc) * 96 + f * 4);
            bf16x4 bv = { (bf16)v.x, (bf16)v.y, (bf16)v.z, (bf16)v.w };
            *(bf16x4*)&ldsA[pix * XS_STR + f * 4] = bv;
        }
        bf16x4 z = { (bf16)0.f, (bf16)0.f, (bf16)0.f, (bf16)0.f };
        for (int t = tid; t < 15 * 24; t += 256) {   // zero M-pad rows 49..63
            int row = 49 + t / 24, f = t - (t / 24) * 24;
            *(bf16x4*)&ldsA[row * XS_STR + f * 4] = z;
        }
    }
    __syncthreads();   // b1: x staged

    // ---------------- Phase 1a: load x A-fragments into registers ----------------
    bf16x8 afr[4][3];
    #pragma unroll
    for (int mt = 0; mt < 4; ++mt)
        #pragma unroll
        for (int ks = 0; ks < 3; ++ks)
            afr[mt][ks] = *(const bf16x8*)&ldsA[(mt * 16 + lm) * XS_STR + ks * 32 + lq * 8];
    __syncthreads();   // b2: region A free -> v^T may be written

    // ---------------- Phase 1b: QKV = xs @ qkv_w + b  (M=64,N=288,K=96) ----------------
    // q,k -> region B row-major [64][QK_STR]; v -> region A as swizzled v^T [96][64]
    for (int nt = wid; nt < 18; nt += 4) {
        const int j = nt * 16 + lm;
        bf16x8 bfr[3];
        #pragma unroll
        for (int ks = 0; ks < 3; ++ks)
            bfr[ks] = *(const bf16x8*)&qkvwT[(size_t)j * 96 + ks * 32 + lq * 8];
        const float bias = qkv_b[j];
        f32x4 acc[4];
        #pragma unroll
        for (int mt = 0; mt < 4; ++mt) acc[mt] = (f32x4){bias, bias, bias, bias};
        #pragma unroll
        for (int ks = 0; ks < 3; ++ks)
            #pragma unroll
            for (int mt = 0; mt < 4; ++mt)
                acc[mt] = MFMA16(afr[mt][ks], bfr[ks], acc[mt]);
        if (j < 192) {      // q or k (wave-uniform branch)
            #pragma unroll
            for (int mt = 0; mt < 4; ++mt)
                #pragma unroll
                for (int i = 0; i < 4; ++i)
                    ldsB[(mt * 16 + lq * 4 + i) * QK_STR + j] = (bf16)acc[mt][i];
        } else {            // v -> v^T[d][t], XOR-swizzled 8-elem groups
            const int d = j - 192;
            #pragma unroll
            for (int mt = 0; mt < 4; ++mt) {
                bf16x4 pv = { (bf16)acc[mt][0], (bf16)acc[mt][1],
                              (bf16)acc[mt][2], (bf16)acc[mt][3] };
                const int pg = (mt * 2 + (lq >> 1)) ^ (d & 7);
                *(bf16x4*)&ldsA[d * 64 + pg * 8 + (lq & 1) * 4] = pv;
            }
        }
    }
    __syncthreads();   // b3: q,k,v^T ready

    // ---------------- Phase 2a: load q,k fragments (reads region B) ----------------
    bf16x8 aq[4], bk[4];
    if (wid < 3) {
        const int h = wid;
        #pragma unroll
        for (int mt = 0; mt < 4; ++mt)
            aq[mt] = *(const bf16x8*)&ldsB[(mt * 16 + lm) * QK_STR + h * 32 + lq * 8];
        #pragma unroll
        for (int nt = 0; nt < 4; ++nt)
            bk[nt] = *(const bf16x8*)&ldsB[(nt * 16 + lm) * QK_STR + 96 + h * 32 + lq * 8];
    }
    __syncthreads();   // b4: region B free -> S may be written

    // ---------------- Phase 2b: S = softmax(qk^T), P->LDS, O = P@V ----------------
    f32x4 oacc[4][2];
    if (wid < 3) {
        const int h = wid;
        const f32x4 zf = {0.f, 0.f, 0.f, 0.f};
        const float scale = 0.17677669529663687f;  // 1/sqrt(32)
        const float log2e = 1.4426950408889634f;
        bf16* Sb = &ldsB[h * S_HEAD];

        // per m-tile: QK^T (4 MFMA), masked softmax, write P rows (keeps VGPRs low)
        #pragma unroll
        for (int mt = 0; mt < 4; ++mt) {
            f32x4 s[4];
            #pragma unroll
            for (int nt = 0; nt < 4; ++nt)
                s[nt] = MFMA16(aq[mt], bk[nt], zf);
            #pragma unroll
            for (int i = 0; i < 4; ++i) {
                float v[4];
                float mx = -3.0e38f;
                #pragma unroll
                for (int nt = 0; nt < 4; ++nt) {
                    const bool valid = (nt * 16 + lm) < 49;
                    v[nt] = valid ? s[nt][i] * scale : -3.0e38f;
                    mx = fmaxf(mx, v[nt]);
                }
                mx = fmaxf(mx, __shfl_xor(mx, 1));
                mx = fmaxf(mx, __shfl_xor(mx, 2));
                mx = fmaxf(mx, __shfl_xor(mx, 4));
                mx = fmaxf(mx, __shfl_xor(mx, 8));
                float p[4], sum = 0.f;
                #pragma unroll
                for (int nt = 0; nt < 4; ++nt) {
                    const bool valid = (nt * 16 + lm) < 49;
                    p[nt] = valid ? exp2f((v[nt] - mx) * log2e) : 0.f;
                    sum += p[nt];
                }
                sum += __shfl_xor(sum, 1);
                sum += __shfl_xor(sum, 2);
                sum += __shfl_xor(sum, 4);
                sum += __shfl_xor(sum, 8);
                const float rinv = __builtin_amdgcn_rcpf(sum);
                const int row = mt * 16 + lq * 4 + i;
                #pragma unroll
                for (int nt = 0; nt < 4; ++nt)
                    Sb[row * SB_STR + nt * 16 + lm] = (bf16)(p[nt] * rinv);
            }
        }

        // PV: O_h = P @ V  (M=64, N=32, K=64); v^T read swizzled from region A
        #pragma unroll
        for (int mt = 0; mt < 4; ++mt)
            #pragma unroll
            for (int nt = 0; nt < 2; ++nt) oacc[mt][nt] = zf;
        #pragma unroll
        for (int ks = 0; ks < 2; ++ks) {
            bf16x8 ap[4], bv[2];
            #pragma unroll
            for (int mt = 0; mt < 4; ++mt)
                ap[mt] = *(const bf16x8*)&Sb[(mt * 16 + lm) * SB_STR + ks * 32 + lq * 8];
            #pragma unroll
            for (int nt = 0; nt < 2; ++nt) {
                const int drow = h * 32 + nt * 16 + lm;
                const int pg = (ks * 4 + lq) ^ (drow & 7);
                bv[nt] = *(const bf16x8*)&ldsA[drow * 64 + pg * 8];
            }
            #pragma unroll
            for (int mt = 0; mt < 4; ++mt)
                #pragma unroll
                for (int nt = 0; nt < 2; ++nt)
                    oacc[mt][nt] = MFMA16(ap[mt], bv[nt], oacc[mt][nt]);
        }
    }
    __syncthreads();   // b5: all S reads done -> O may overwrite region B

    // ---------------- Phase 2c: write O (region B, [64][XS_STR]) ----------------
    if (wid < 3) {
        const int h = wid;
        #pragma unroll
        for (int mt = 0; mt < 4; ++mt)
            #pragma unroll
            for (int nt = 0; nt < 2; ++nt)
                #pragma unroll
                for (int i = 0; i < 4; ++i)
                    ldsB[(mt * 16 + lq * 4 + i) * XS_STR + h * 32 + nt * 16 + lm] =
                        (bf16)oacc[mt][nt][i];
    }
    __syncthreads();   // b6: O ready

    // ---------------- Phase 3: proj (M=64,N=96,K=96), wave w owns m-tile w ----------------
    {
        const int mt = wid;
        bf16x8 ao[3];
        #pragma unroll
        for (int ks = 0; ks < 3; ++ks)
            ao[ks] = *(const bf16x8*)&ldsB[(mt * 16 + lm) * XS_STR + ks * 32 + lq * 8];
        #pragma unroll
        for (int nt = 0; nt < 6; ++nt) {
            const int j = nt * 16 + lm;
            bf16x8 bp[3];
            #pragma unroll
            for (int ks = 0; ks < 3; ++ks)
                bp[ks] = *(const bf16x8*)&projwT[(size_t)j * 96 + ks * 32 + lq * 8];
            const float bias = proj_b[j];
            f32x4 acc = {bias, bias, bias, bias};
            #pragma unroll
            for (int ks = 0; ks < 3; ++ks)
                acc = MFMA16(ao[ks], bp[ks], acc);
            #pragma unroll
            for (int i = 0; i < 4; ++i) {
                const int l = mt * 16 + lq * 4 + i;
                if (l < 49) {
                    const int pr = l / 7, pc = l - pr * 7;
                    out[((size_t)(b * 224 + h0 + pr) * 224 + (w0 + pc)) * 96 + j] = acc[i];
                }
            }
        }
    }
}

extern "C" void kernel_launch(void* const* d_in, const int* in_sizes, int n_in,
                              void* d_out, int out_size, void* d_ws, size_t ws_size,
                              hipStream_t stream) {
    const float* x      = (const float*)d_in[0];
    const float* qkv_w  = (const float*)d_in[1];
    const float* qkv_b  = (const float*)d_in[2];
    const float* proj_w = (const float*)d_in[3];
    const float* proj_b = (const float*)d_in[4];
    float* out = (float*)d_out;

    bf16* wT = (bf16*)d_ws;                 // 288*96 + 96*96 bf16 = 73728 B
    const int n_w = 288 * 96 + 96 * 96;
    prep_weights<<<(n_w + 255) / 256, 256, 0, stream>>>(qkv_w, proj_w, wT);
    win_attn_kernel<<<8192, 256, 0, stream>>>(x, qkv_b, proj_b,
                                              wT, wT + 288 * 96, out);
}